// Round 5
// baseline (932.591 us; speedup 1.0000x reference)
//
#include <hip/hip_runtime.h>
#include <hip/hip_bf16.h>

typedef __attribute__((ext_vector_type(8))) short short8;
typedef __attribute__((ext_vector_type(4))) float f32x4;

#define D_MODEL 512
#define BN 128
#define NT 16
#define B_TILE 16384   // fp32: 128 rows x 128B (k-slice of 32)

__device__ __forceinline__ void gload16(const void* g, void* l) {
    typedef const __attribute__((address_space(1))) unsigned GT;
    typedef __attribute__((address_space(3))) unsigned LT;
    __builtin_amdgcn_global_load_lds((GT*)g, (LT*)l, 16, 0, 0);
}

__device__ __forceinline__ short f2bf(float f) {
    unsigned u = __builtin_bit_cast(unsigned, f);
    unsigned r = (u + 0x7fffu + ((u >> 16) & 1u)) >> 16;
    return (short)r;
}

__device__ __forceinline__ short8 cvt8(const f32x4& a, const f32x4& b) {
    union { __hip_bfloat162 h[4]; short8 s; } u;
    u.h[0] = __float22bfloat162_rn(make_float2(a[0], a[1]));
    u.h[1] = __float22bfloat162_rn(make_float2(a[2], a[3]));
    u.h[2] = __float22bfloat162_rn(make_float2(b[0], b[1]));
    u.h[3] = __float22bfloat162_rn(make_float2(b[2], b[3]));
    return u.s;
}

// Kernel 1: cond[b][k] = ent[s_ent[b]][k] + rel[relation[b]][k]  (bf16 -> ws), a2[b] = ||cond||^2
__global__ void prep_kernel(const int* __restrict__ s_ent, const int* __restrict__ rel,
                            const float* __restrict__ ent, const float* __restrict__ relemb,
                            short* __restrict__ condb, float* __restrict__ a2) {
    const int b = blockIdx.x;
    const int t = threadIdx.x;
    const float4 v = *(const float4*)(ent + (size_t)s_ent[b] * D_MODEL + t * 4);
    const float4 w = *(const float4*)(relemb + (size_t)rel[b] * D_MODEL + t * 4);
    float c0 = v.x + w.x, c1 = v.y + w.y, c2 = v.z + w.z, c3 = v.w + w.w;
    float sq = c0 * c0 + c1 * c1 + c2 * c2 + c3 * c3;

    short4 s;
    s.x = f2bf(c0); s.y = f2bf(c1); s.z = f2bf(c2); s.w = f2bf(c3);
    *(short4*)(condb + (size_t)b * D_MODEL + t * 4) = s;

    #pragma unroll
    for (int off = 1; off < 64; off <<= 1) sq += __shfl_xor(sq, off);
    __shared__ float red[2];
    if ((t & 63) == 0) red[t >> 6] = sq;
    __syncthreads();
    if (t == 0) a2[b] = red[0] + red[1];
}

// Kernel 2: BM=256, BN=128, BK=32, 512 thr = 8 waves (4M x 2N).
// A-fragments straight from global (cond 256KB, L2-resident), distance-1 reg prefetch.
// B: fp32 gload_lds ring-3 (source-swizzled), counted vmcnt(6) keeps B(t+1) in flight
// across every barrier. LDS = 48 KiB -> 3 blocks/CU (24 waves, 3 independent phases).
__global__ __launch_bounds__(512, 6)
void score_kernel(const float* __restrict__ ent, const short* __restrict__ condb,
                  const float* __restrict__ a2, float* __restrict__ out, const int n_ent) {
    __shared__ __align__(16) unsigned char lds[3 * B_TILE];  // 48 KiB
    unsigned char* Bl = lds;

    const int tid  = threadIdx.x;
    const int lane = tid & 63;
    const int w    = tid >> 6, wm = w >> 1, wn = w & 1;
    const int lrow = lane & 15, g4 = lane >> 4;
    const int nbase = blockIdx.x * BN;

    // B staging: LDS linear at tid*16 (+8192); XOR-swizzle on the GLOBAL source (rule #21)
    const int p0 = tid * 16, p1 = p0 + 8192;
    const int br0 = p0 >> 7, br1 = p1 >> 7;                 // rows 0..63 / 64..127
    const long long gr0 = min(nbase + br0, n_ent - 1);      // clamp tail block
    const long long gr1 = min(nbase + br1, n_ent - 1);
    const char* gB0 = (const char*)ent + gr0 * 2048 + ((p0 & 127) ^ ((br0 & 7) << 4));
    const char* gB1 = (const char*)ent + gr1 * 2048 + ((p1 & 127) ^ ((br1 & 7) << 4));

    // B LDS read offsets (swizzled; verbatim champion-R2)
    int boff0[4], boff1[4];
    #pragma unroll
    for (int f = 0; f < 4; ++f) {
        const int rb = wn * 64 + f * 16 + lrow;
        const int sw = (rb & 7) << 4;
        boff0[f] = rb * 128 + ((g4 * 32) ^ sw);
        boff1[f] = rb * 128 + ((g4 * 32 + 16) ^ sw);
    }

    // A fragment source: cond row (wm*64 + f*16 + lrow), k-chunk g4*8 shorts, step t -> +32 shorts
    const short* abase = condb + (size_t)(wm * 64 + lrow) * D_MODEL + g4 * 8;

    f32x4 acc[4][4] = {};
    float sq[4] = {0.f, 0.f, 0.f, 0.f};

    // prologue: issue B(0), Af(0), B(1)  -> outstanding [B0 B0 Af0 Af0 Af0 Af0 B1 B1]
    gload16(gB0, Bl + p0);
    gload16(gB1, Bl + p1);
    short8 afA0 = *(const short8*)(abase);
    short8 afA1 = *(const short8*)(abase + 8192);
    short8 afA2 = *(const short8*)(abase + 16384);
    short8 afA3 = *(const short8*)(abase + 24576);
    short8 afB0, afB1, afB2, afB3;
    gload16(gB0 + 128, Bl + B_TILE + p0);
    gload16(gB1 + 128, Bl + B_TILE + p1);

// step T: vmcnt(VM) retires B(T); barrier; prefetch Af(T+1); issue B(T+2) dma;
// compute tile T from AFC regs + Bl[T%3] (cvt fp32->bf16 on read; wm==0 accumulates b2).
#define KSTEP(T, AC0, AC1, AC2, AC3, AN0, AN1, AN2, AN3, VM, DO_A, DO_B)                  \
  {                                                                                        \
    asm volatile("s_waitcnt vmcnt(" #VM ")" ::: "memory");                                 \
    __builtin_amdgcn_s_barrier();                                                          \
    if (DO_A) {                                                                            \
      AN0 = *(const short8*)(abase + ((T) + 1) * 32);                                      \
      AN1 = *(const short8*)(abase + 8192  + ((T) + 1) * 32);                              \
      AN2 = *(const short8*)(abase + 16384 + ((T) + 1) * 32);                              \
      AN3 = *(const short8*)(abase + 24576 + ((T) + 1) * 32);                              \
    }                                                                                      \
    if (DO_B) {                                                                            \
      unsigned char* bd = Bl + (((T) + 2) % 3) * B_TILE;                                   \
      gload16(gB0 + ((T) + 2) * 128, bd + p0);                                             \
      gload16(gB1 + ((T) + 2) * 128, bd + p1);                                             \
    }                                                                                      \
    const unsigned char* bb = Bl + ((T) % 3) * B_TILE;                                     \
    _Pragma("unroll")                                                                      \
    for (int fn = 0; fn < 4; ++fn) {                                                       \
      const f32x4 v0 = *(const f32x4*)(bb + boff0[fn]);                                    \
      const f32x4 v1 = *(const f32x4*)(bb + boff1[fn]);                                    \
      if (wm == 0)                                                                         \
        sq[fn] += v0[0]*v0[0] + v0[1]*v0[1] + v0[2]*v0[2] + v0[3]*v0[3]                    \
                + v1[0]*v1[0] + v1[1]*v1[1] + v1[2]*v1[2] + v1[3]*v1[3];                   \
      const short8 bf = cvt8(v0, v1);                                                      \
      acc[0][fn] = __builtin_amdgcn_mfma_f32_16x16x32_bf16(AC0, bf, acc[0][fn], 0, 0, 0);  \
      acc[1][fn] = __builtin_amdgcn_mfma_f32_16x16x32_bf16(AC1, bf, acc[1][fn], 0, 0, 0);  \
      acc[2][fn] = __builtin_amdgcn_mfma_f32_16x16x32_bf16(AC2, bf, acc[2][fn], 0, 0, 0);  \
      acc[3][fn] = __builtin_amdgcn_mfma_f32_16x16x32_bf16(AC3, bf, acc[3][fn], 0, 0, 0);  \
    }                                                                                      \
  }

    KSTEP(0,  afA0,afA1,afA2,afA3, afB0,afB1,afB2,afB3, 6, true, true)
    KSTEP(1,  afB0,afB1,afB2,afB3, afA0,afA1,afA2,afA3, 6, true, true)
    KSTEP(2,  afA0,afA1,afA2,afA3, afB0,afB1,afB2,afB3, 6, true, true)
    KSTEP(3,  afB0,afB1,afB2,afB3, afA0,afA1,afA2,afA3, 6, true, true)
    KSTEP(4,  afA0,afA1,afA2,afA3, afB0,afB1,afB2,afB3, 6, true, true)
    KSTEP(5,  afB0,afB1,afB2,afB3, afA0,afA1,afA2,afA3, 6, true, true)
    KSTEP(6,  afA0,afA1,afA2,afA3, afB0,afB1,afB2,afB3, 6, true, true)
    KSTEP(7,  afB0,afB1,afB2,afB3, afA0,afA1,afA2,afA3, 6, true, true)
    KSTEP(8,  afA0,afA1,afA2,afA3, afB0,afB1,afB2,afB3, 6, true, true)
    KSTEP(9,  afB0,afB1,afB2,afB3, afA0,afA1,afA2,afA3, 6, true, true)
    KSTEP(10, afA0,afA1,afA2,afA3, afB0,afB1,afB2,afB3, 6, true, true)
    KSTEP(11, afB0,afB1,afB2,afB3, afA0,afA1,afA2,afA3, 6, true, true)
    KSTEP(12, afA0,afA1,afA2,afA3, afB0,afB1,afB2,afB3, 6, true, true)
    KSTEP(13, afB0,afB1,afB2,afB3, afA0,afA1,afA2,afA3, 6, true, true)
    KSTEP(14, afA0,afA1,afA2,afA3, afB0,afB1,afB2,afB3, 6, true, false)
    KSTEP(15, afB0,afB1,afB2,afB3, afA0,afA1,afA2,afA3, 4, false, false)
#undef KSTEP

    // b2[n] from wm==0 waves (their read frags cover all 128 rows x all k):
    // reduce the 4 g4-groups (lanes +-16, +-32), write rows.
    // Store into Bl[1] (tile 13's buffer: quiescent since barrier 14; disjoint from
    // Bl[0] which other waves may still be reading for step 15).
    float* b2s = (float*)(lds + B_TILE);
    if (wm == 0) {
        #pragma unroll
        for (int fn = 0; fn < 4; ++fn) {
            sq[fn] += __shfl_xor(sq[fn], 16);
            sq[fn] += __shfl_xor(sq[fn], 32);
        }
        if (lane < 16) {
            #pragma unroll
            for (int fn = 0; fn < 4; ++fn) b2s[wn * 64 + fn * 16 + lane] = sq[fn];
        }
    }
    __syncthreads();

    // epilogue: d2 = a2[m] - 2*ab + b2[n]; score = -sqrt(max(d2, 1e-12))
    #pragma unroll
    for (int fm = 0; fm < 4; ++fm) {
        const int m0 = wm * 64 + fm * 16 + g4 * 4;
        const f32x4 a2v = *(const f32x4*)(a2 + m0);
        #pragma unroll
        for (int fn = 0; fn < 4; ++fn) {
            const int nl = wn * 64 + fn * 16 + lrow;
            const int ng = nbase + nl;
            if (ng < n_ent) {
                const float b2v = b2s[nl];
                #pragma unroll
                for (int r = 0; r < 4; ++r) {
                    float d2 = a2v[r] - 2.f * acc[fm][fn][r] + b2v;
                    out[(size_t)(m0 + r) * n_ent + ng] = -sqrtf(fmaxf(d2, 1e-12f));
                }
            }
        }
    }
}

extern "C" void kernel_launch(void* const* d_in, const int* in_sizes, int n_in,
                              void* d_out, int out_size, void* d_ws, size_t ws_size,
                              hipStream_t stream) {
    const int*   s_ent  = (const int*)d_in[0];
    const int*   rel    = (const int*)d_in[1];
    // d_in[2] = o_ent, d_in[3] = time : unused by reference forward
    const float* ent    = (const float*)d_in[4];
    const float* relemb = (const float*)d_in[5];
    float* out = (float*)d_out;

    const int bs    = in_sizes[0];              // 256
    const int n_ent = in_sizes[4] / D_MODEL;    // 200000

    short* condb = (short*)d_ws;                               // bs*512 bf16 = 256KB
    float* a2    = (float*)((char*)d_ws + (size_t)bs * D_MODEL * 2);

    prep_kernel<<<bs, 128, 0, stream>>>(s_ent, rel, ent, relemb, condb, a2);

    const int ntiles = (n_ent + BN - 1) / BN;   // 1563
    score_kernel<<<ntiles, 512, 0, stream>>>(ent, condb, a2, out, n_ent);
}

// Round 6
// 197.640 us; speedup vs baseline: 4.7186x; 4.7186x over previous
//
#include <hip/hip_runtime.h>
#include <hip/hip_bf16.h>

typedef __attribute__((ext_vector_type(8))) short short8;
typedef __attribute__((ext_vector_type(4))) float f32x4;

#define D_MODEL 512
#define BN 64
#define NT 16
#define B_TILE 8192   // fp32: 64 rows x 128B (k-slice of 32)

__device__ __forceinline__ void gload16(const void* g, void* l) {
    typedef const __attribute__((address_space(1))) unsigned GT;
    typedef __attribute__((address_space(3))) unsigned LT;
    __builtin_amdgcn_global_load_lds((GT*)g, (LT*)l, 16, 0, 0);
}

__device__ __forceinline__ short f2bf(float f) {
    unsigned u = __builtin_bit_cast(unsigned, f);
    unsigned r = (u + 0x7fffu + ((u >> 16) & 1u)) >> 16;
    return (short)r;
}

__device__ __forceinline__ short8 cvt8(const f32x4& a, const f32x4& b) {
    union { __hip_bfloat162 h[4]; short8 s; } u;
    u.h[0] = __float22bfloat162_rn(make_float2(a[0], a[1]));
    u.h[1] = __float22bfloat162_rn(make_float2(a[2], a[3]));
    u.h[2] = __float22bfloat162_rn(make_float2(b[0], b[1]));
    u.h[3] = __float22bfloat162_rn(make_float2(b[2], b[3]));
    return u.s;
}

// Kernel 1: cond[b][k] = ent[s_ent[b]][k] + rel[relation[b]][k]  (bf16 -> ws), a2[b] = ||cond||^2
__global__ void prep_kernel(const int* __restrict__ s_ent, const int* __restrict__ rel,
                            const float* __restrict__ ent, const float* __restrict__ relemb,
                            short* __restrict__ condb, float* __restrict__ a2) {
    const int b = blockIdx.x;
    const int t = threadIdx.x;
    const float4 v = *(const float4*)(ent + (size_t)s_ent[b] * D_MODEL + t * 4);
    const float4 w = *(const float4*)(relemb + (size_t)rel[b] * D_MODEL + t * 4);
    float c0 = v.x + w.x, c1 = v.y + w.y, c2 = v.z + w.z, c3 = v.w + w.w;
    float sq = c0 * c0 + c1 * c1 + c2 * c2 + c3 * c3;

    short4 s;
    s.x = f2bf(c0); s.y = f2bf(c1); s.z = f2bf(c2); s.w = f2bf(c3);
    *(short4*)(condb + (size_t)b * D_MODEL + t * 4) = s;

    #pragma unroll
    for (int off = 1; off < 64; off <<= 1) sq += __shfl_xor(sq, off);
    __shared__ float red[2];
    if ((t & 63) == 0) red[t >> 6] = sq;
    __syncthreads();
    if (t == 0) a2[b] = red[0] + red[1];
}

// Kernel 2: BM=256 (all queries), BN=64, BK=32; 256 thr = 4 waves, wave w owns rows w*64..w*64+63.
// A-frags per-wave from L2 (cond 256KB resident; issued BEFORE B-DMA so the compiler's af-wait
// lands at vmcnt(2), draining B(t) and keeping B(t+2) in flight across the barrier).
// B: fp32 gload_lds ring-3 (source-swizzled), issue distance 2.
// LDS 24 KiB + VGPR<=128 -> 4 blocks/CU = 4 independent barrier domains.
__global__ __launch_bounds__(256, 4)
void score_kernel(const float* __restrict__ ent, const short* __restrict__ condb,
                  const float* __restrict__ a2, float* __restrict__ out, const int n_ent) {
    __shared__ __align__(16) unsigned char lds[3 * B_TILE];  // 24 KiB
    unsigned char* Bl = lds;

    const int tid  = threadIdx.x;
    const int lane = tid & 63;
    const int wm   = tid >> 6;              // 0..3
    const int lrow = lane & 15, g4 = lane >> 4;
    const long long nbase = (long long)blockIdx.x * BN;

    // B staging: LDS linear at tid*16 (+4096); XOR-swizzle on the GLOBAL source (rule #21)
    const int p0 = tid * 16, p1 = p0 + 4096;
    const int br0 = p0 >> 7, br1 = p1 >> 7;                 // rows 0..31 / 32..63
    const long long gr0 = min(nbase + br0, (long long)(n_ent - 1));   // clamp tail block
    const long long gr1 = min(nbase + br1, (long long)(n_ent - 1));
    const char* gB0 = (const char*)ent + gr0 * 2048 + ((p0 & 127) ^ ((br0 & 7) << 4));
    const char* gB1 = (const char*)ent + gr1 * 2048 + ((p1 & 127) ^ ((br1 & 7) << 4));

    // B LDS read offsets (swizzled; same family as champion R2 -> 2-way = free)
    int boff0[4], boff1[4];
    #pragma unroll
    for (int f = 0; f < 4; ++f) {
        const int rb = f * 16 + lrow;
        const int sw = (rb & 7) << 4;
        boff0[f] = rb * 128 + ((g4 * 32) ^ sw);
        boff1[f] = rb * 128 + ((g4 * 32 + 16) ^ sw);
    }

    // A fragment source: cond row (wm*64 + f*16 + lrow), k-chunk g4*8 shorts; step t -> +32 shorts.
    // 4 g4-groups of one row share a single 64B L2 line -> fully coalesced.
    const short* abase = condb + (size_t)(wm * 64 + lrow) * D_MODEL + g4 * 8;

    f32x4 acc[4][4] = {};
    float sq[4] = {0.f, 0.f, 0.f, 0.f};

    // prologue: issue B(0), B(1)  (4 outstanding VMEM per wave)
    gload16(gB0, Bl + p0);
    gload16(gB1, Bl + p1);
    gload16(gB0 + 128, Bl + B_TILE + p0);
    gload16(gB1 + 128, Bl + B_TILE + p1);

    #pragma unroll
    for (int t = 0; t < NT; ++t) {
        // manual counted wait: B(t) (and older) landed; B(t+1) may stay in flight
        asm volatile("s_waitcnt vmcnt(2)" ::: "memory");
        __builtin_amdgcn_s_barrier();

        // A frags FIRST (older than the next DMA -> their wait won't drain B(t+2))
        const short8 af0 = *(const short8*)(abase + t * 32);
        const short8 af1 = *(const short8*)(abase + t * 32 + 8192);
        const short8 af2 = *(const short8*)(abase + t * 32 + 16384);
        const short8 af3 = *(const short8*)(abase + t * 32 + 24576);

        // issue B(t+2) DMA
        if (t + 2 < NT) {
            unsigned char* bd = Bl + ((t + 2) % 3) * B_TILE;
            gload16(gB0 + (t + 2) * 128, bd + p0);
            gload16(gB1 + (t + 2) * 128, bd + p1);
        }

        const unsigned char* bb = Bl + (t % 3) * B_TILE;
        #pragma unroll
        for (int fn = 0; fn < 4; ++fn) {
            const f32x4 v0 = *(const f32x4*)(bb + boff0[fn]);
            const f32x4 v1 = *(const f32x4*)(bb + boff1[fn]);
            if (wm == 0)   // b2 accumulated once (wave 0 reads all 64 rows x full k)
                sq[fn] += v0[0]*v0[0] + v0[1]*v0[1] + v0[2]*v0[2] + v0[3]*v0[3]
                        + v1[0]*v1[0] + v1[1]*v1[1] + v1[2]*v1[2] + v1[3]*v1[3];
            const short8 bf = cvt8(v0, v1);
            acc[0][fn] = __builtin_amdgcn_mfma_f32_16x16x32_bf16(af0, bf, acc[0][fn], 0, 0, 0);
            acc[1][fn] = __builtin_amdgcn_mfma_f32_16x16x32_bf16(af1, bf, acc[1][fn], 0, 0, 0);
            acc[2][fn] = __builtin_amdgcn_mfma_f32_16x16x32_bf16(af2, bf, acc[2][fn], 0, 0, 0);
            acc[3][fn] = __builtin_amdgcn_mfma_f32_16x16x32_bf16(af3, bf, acc[3][fn], 0, 0, 0);
        }
    }

    // b2[n]: wave 0 reduces its 4 g4-groups (lanes +-16, +-32) and publishes 64 rows.
    // Bl[1] is quiescent (last written by B(13) DMA, drained by step-14's waits; step 15 reads Bl[0]).
    float* b2s = (float*)(lds + B_TILE);
    if (wm == 0) {
        #pragma unroll
        for (int fn = 0; fn < 4; ++fn) {
            sq[fn] += __shfl_xor(sq[fn], 16);
            sq[fn] += __shfl_xor(sq[fn], 32);
        }
        if (lane < 16) {
            #pragma unroll
            for (int fn = 0; fn < 4; ++fn) b2s[fn * 16 + lane] = sq[fn];
        }
    }
    __syncthreads();

    // epilogue: d2 = a2[m] - 2*ab + b2[n]; score = -sqrt(max(d2, 1e-12))
    #pragma unroll
    for (int fm = 0; fm < 4; ++fm) {
        const int m0 = wm * 64 + fm * 16 + g4 * 4;
        const f32x4 a2v = *(const f32x4*)(a2 + m0);
        #pragma unroll
        for (int fn = 0; fn < 4; ++fn) {
            const int nl = fn * 16 + lrow;
            const long long ng = nbase + nl;
            if (ng < n_ent) {
                const float b2v = b2s[nl];
                #pragma unroll
                for (int r = 0; r < 4; ++r) {
                    float d2 = a2v[r] - 2.f * acc[fm][fn][r] + b2v;
                    out[(size_t)(m0 + r) * n_ent + ng] = -sqrtf(fmaxf(d2, 1e-12f));
                }
            }
        }
    }
}

extern "C" void kernel_launch(void* const* d_in, const int* in_sizes, int n_in,
                              void* d_out, int out_size, void* d_ws, size_t ws_size,
                              hipStream_t stream) {
    const int*   s_ent  = (const int*)d_in[0];
    const int*   rel    = (const int*)d_in[1];
    // d_in[2] = o_ent, d_in[3] = time : unused by reference forward
    const float* ent    = (const float*)d_in[4];
    const float* relemb = (const float*)d_in[5];
    float* out = (float*)d_out;

    const int bs    = in_sizes[0];              // 256
    const int n_ent = in_sizes[4] / D_MODEL;    // 200000

    short* condb = (short*)d_ws;                               // bs*512 bf16 = 256KB
    float* a2    = (float*)((char*)d_ws + (size_t)bs * D_MODEL * 2);

    prep_kernel<<<bs, 128, 0, stream>>>(s_ent, rel, ent, relemb, condb, a2);

    const int ntiles = (n_ent + BN - 1) / BN;   // 3125
    score_kernel<<<ntiles, 256, 0, stream>>>(ent, condb, a2, out, n_ent);
}